// Round 1
// baseline (1602.234 us; speedup 1.0000x reference)
//
#include <hip/hip_runtime.h>
#include <math.h>

#define N_NODES 100000
#define N_EDGES 3200000
#define N_GRAPHS 64

// ---------------- kernels ----------------

__global__ void k_init_deg(unsigned int* __restrict__ deg) {
    int n = blockIdx.x * blockDim.x + threadIdx.x;
    if (n < N_NODES) deg[n] = 1u;  // self-loop
}

__global__ void k_count_deg(const int* __restrict__ dst, unsigned int* __restrict__ deg) {
    int e = blockIdx.x * blockDim.x + threadIdx.x;
    if (e < N_EDGES) atomicAdd(&deg[dst[e]], 1u);
}

// dinv[n] = 1/sqrt(deg); s[n] = x[n]*dinv[n]; also count nodes per graph
__global__ void k_dinv_s(const unsigned int* __restrict__ deg, const float* __restrict__ x,
                         const int* __restrict__ batch,
                         float* __restrict__ dinv, float* __restrict__ s,
                         float* __restrict__ gcnt) {
    int n = blockIdx.x * blockDim.x + threadIdx.x;
    if (n < N_NODES) {
        float di = 1.0f / sqrtf((float)deg[n]);  // deg >= 1 always (self-loop)
        dinv[n] = di;
        s[n] = x[n] * di;
        atomicAdd(&gcnt[batch[n]], 1.0f);
    }
}

// agg1[dst] += s[src]  (scalar layer-1 aggregation)
__global__ void k_edge_agg1(const int* __restrict__ src, const int* __restrict__ dst,
                            const float* __restrict__ s, float* __restrict__ agg1) {
    int e = blockIdx.x * blockDim.x + threadIdx.x;
    if (e < N_EDGES) atomicAdd(&agg1[dst[e]], s[src[e]]);
}

// Per node: t = dinv*(agg1 + s); h1[j] = relu(t*W1[j]+b1[j]);
// p[k] = sum_j h1[j]*W2[j,k]; q[n,k] = p[k]*dinv[n]
__global__ void k_node_mlp(const float* __restrict__ dinv, const float* __restrict__ s,
                           const float* __restrict__ agg1,
                           const float* __restrict__ W1, const float* __restrict__ b1,
                           const float* __restrict__ W2,
                           float* __restrict__ q) {
    __shared__ float sW2[64 * 32];
    __shared__ float sW1[64];
    __shared__ float sb1[64];
    for (int i = threadIdx.x; i < 64 * 32; i += blockDim.x) sW2[i] = W2[i];
    if (threadIdx.x < 64) {
        sW1[threadIdx.x] = W1[threadIdx.x];
        sb1[threadIdx.x] = b1[threadIdx.x];
    }
    __syncthreads();

    int n = blockIdx.x * blockDim.x + threadIdx.x;
    if (n >= N_NODES) return;

    float di = dinv[n];
    float t = di * (agg1[n] + s[n]);  // = dinv*agg1 + x*dinv^2 (self-loop folded in)

    float p[32];
#pragma unroll
    for (int k = 0; k < 32; k++) p[k] = 0.0f;

    for (int j = 0; j < 64; j++) {
        float h = fmaxf(t * sW1[j] + sb1[j], 0.0f);
#pragma unroll
        for (int k = 0; k < 32; k++) p[k] += h * sW2[j * 32 + k];
    }

#pragma unroll
    for (int k = 0; k < 32; k++) q[(size_t)n * 32 + k] = p[k] * di;
}

// agg2[dst,k] += q[src,k] — 32 lanes per edge, lane k handles feature k
__global__ void k_edge_agg2(const int* __restrict__ src, const int* __restrict__ dst,
                            const float* __restrict__ q, float* __restrict__ agg2) {
    long long t = (long long)blockIdx.x * blockDim.x + threadIdx.x;
    int e = (int)(t >> 5);
    int k = (int)(t & 31);
    if (e < N_EDGES) {
        int si = src[e];  // broadcast load within the 32-lane group
        int di = dst[e];
        atomicAdd(&agg2[(size_t)di * 32 + k], q[(size_t)si * 32 + k]);
    }
}

// out2[n,k] = relu(dinv*(agg2 + q) + b2); accumulate into graph sums
__global__ void k_final_nodes(const float* __restrict__ dinv, const float* __restrict__ q,
                              const float* __restrict__ agg2, const float* __restrict__ b2,
                              const int* __restrict__ batch,
                              float* __restrict__ gsum) {
    long long t = (long long)blockIdx.x * blockDim.x + threadIdx.x;
    int n = (int)(t >> 5);
    int k = (int)(t & 31);
    if (n < N_NODES) {
        float di = dinv[n];
        float v = fmaxf(di * (agg2[(size_t)n * 32 + k] + q[(size_t)n * 32 + k]) + b2[k], 0.0f);
        atomicAdd(&gsum[(size_t)batch[n] * 32 + k], v);
    }
}

// g[b,:] = gsum/cnt; out[b] = sigmoid(g . Wfc + bfc)
__global__ void k_readout(const float* __restrict__ gsum, const float* __restrict__ gcnt,
                          const float* __restrict__ Wfc, const float* __restrict__ bfc,
                          float* __restrict__ out) {
    int b = threadIdx.x;
    if (b < N_GRAPHS) {
        float inv = 1.0f / fmaxf(gcnt[b], 1.0f);
        float acc = bfc[0];
#pragma unroll
        for (int k = 0; k < 32; k++) acc += gsum[b * 32 + k] * inv * Wfc[k];
        out[b] = 1.0f / (1.0f + expf(-acc));
    }
}

// ---------------- launch ----------------

extern "C" void kernel_launch(void* const* d_in, const int* in_sizes, int n_in,
                              void* d_out, int out_size, void* d_ws, size_t ws_size,
                              hipStream_t stream) {
    const float* x    = (const float*)d_in[0];
    const int*   ei   = (const int*)d_in[1];   // [2, E] int32
    const int*   batch= (const int*)d_in[2];
    const float* W1   = (const float*)d_in[3];
    const float* b1   = (const float*)d_in[4];
    const float* W2   = (const float*)d_in[5];
    const float* b2   = (const float*)d_in[6];
    const float* Wfc  = (const float*)d_in[7];
    const float* bfc  = (const float*)d_in[8];
    float* out = (float*)d_out;

    const int* srcIdx = ei;
    const int* dstIdx = ei + N_EDGES;

    // workspace layout (~27.2 MB)
    char* w = (char*)d_ws;
    unsigned int* deg = (unsigned int*)w; w += (size_t)N_NODES * 4;
    float* dinv = (float*)w;              w += (size_t)N_NODES * 4;
    float* sbuf = (float*)w;              w += (size_t)N_NODES * 4;
    float* agg1 = (float*)w;              w += (size_t)N_NODES * 4;
    float* q    = (float*)w;              w += (size_t)N_NODES * 32 * 4;
    float* agg2 = (float*)w;              w += (size_t)N_NODES * 32 * 4;
    float* gsum = (float*)w;              w += (size_t)N_GRAPHS * 32 * 4;
    float* gcnt = (float*)w;              w += (size_t)N_GRAPHS * 4;

    hipMemsetAsync(agg1, 0, (size_t)N_NODES * 4, stream);
    hipMemsetAsync(agg2, 0, (size_t)N_NODES * 32 * 4, stream);
    hipMemsetAsync(gsum, 0, (size_t)N_GRAPHS * 32 * 4, stream);
    hipMemsetAsync(gcnt, 0, (size_t)N_GRAPHS * 4, stream);

    const int B = 256;
    k_init_deg  <<<(N_NODES + B - 1) / B, B, 0, stream>>>(deg);
    k_count_deg <<<(N_EDGES + B - 1) / B, B, 0, stream>>>(dstIdx, deg);
    k_dinv_s    <<<(N_NODES + B - 1) / B, B, 0, stream>>>(deg, x, batch, dinv, sbuf, gcnt);
    k_edge_agg1 <<<(N_EDGES + B - 1) / B, B, 0, stream>>>(srcIdx, dstIdx, sbuf, agg1);
    k_node_mlp  <<<(N_NODES + B - 1) / B, B, 0, stream>>>(dinv, sbuf, agg1, W1, b1, W2, q);

    long long t2 = (long long)N_EDGES * 32;
    k_edge_agg2 <<<(unsigned int)((t2 + B - 1) / B), B, 0, stream>>>(srcIdx, dstIdx, q, agg2);

    long long t3 = (long long)N_NODES * 32;
    k_final_nodes<<<(unsigned int)((t3 + B - 1) / B), B, 0, stream>>>(dinv, q, agg2, b2, batch, gsum);

    k_readout<<<1, 64, 0, stream>>>(gsum, gcnt, Wfc, bfc, out);
}

// Round 2
// 750.898 us; speedup vs baseline: 2.1338x; 2.1338x over previous
//
#include <hip/hip_runtime.h>
#include <math.h>

#define N_NODES 100000
#define N_EDGES 3200000
#define N_GRAPHS 64
#define SCAN_B 256
#define NB_SCAN ((N_NODES + SCAN_B - 1) / SCAN_B)   // 391

// ---------------- degree histogram ----------------

__global__ void k_hist(const int* __restrict__ dst, unsigned int* __restrict__ cnt) {
    int e = blockIdx.x * blockDim.x + threadIdx.x;
    if (e < N_EDGES) atomicAdd(&cnt[dst[e]], 1u);
}

// dinv[n] = 1/sqrt(cnt[n]+1) (self-loop); s[n] = x[n]*dinv[n]
__global__ void k_dinv_s(const unsigned int* __restrict__ cnt, const float* __restrict__ x,
                         float* __restrict__ dinv, float* __restrict__ s) {
    int n = blockIdx.x * blockDim.x + threadIdx.x;
    if (n < N_NODES) {
        float di = 1.0f / sqrtf((float)(cnt[n] + 1u));
        dinv[n] = di;
        s[n] = x[n] * di;
    }
}

// graph node counts via binary search on sorted batch — NO atomics
__global__ void k_gcnt(const int* __restrict__ batch, float* __restrict__ gcnt) {
    __shared__ int lb[N_GRAPHS + 1];
    int b = threadIdx.x;
    if (b <= N_GRAPHS) {
        int lo = 0, hi = N_NODES;
        while (lo < hi) {
            int mid = (lo + hi) >> 1;
            if (batch[mid] < b) lo = mid + 1; else hi = mid;
        }
        lb[b] = lo;
    }
    __syncthreads();
    if (b < N_GRAPHS) gcnt[b] = (float)(lb[b + 1] - lb[b]);
}

// ---------------- CSR build: scan of cnt ----------------

__global__ void k_scan1(const unsigned int* __restrict__ cnt, unsigned int* __restrict__ bsum) {
    __shared__ unsigned int sd[SCAN_B];
    int i = blockIdx.x * SCAN_B + threadIdx.x;
    sd[threadIdx.x] = (i < N_NODES) ? cnt[i] : 0u;
    __syncthreads();
    for (int off = SCAN_B / 2; off > 0; off >>= 1) {
        if (threadIdx.x < off) sd[threadIdx.x] += sd[threadIdx.x + off];
        __syncthreads();
    }
    if (threadIdx.x == 0) bsum[blockIdx.x] = sd[0];
}

__global__ void k_scan2(unsigned int* __restrict__ bsum) {  // exclusive scan of NB_SCAN values, 1 block of 512
    __shared__ unsigned int sd[512];
    int t = threadIdx.x;
    unsigned int v = (t < NB_SCAN) ? bsum[t] : 0u;
    sd[t] = v;
    __syncthreads();
    for (int off = 1; off < 512; off <<= 1) {
        unsigned int tv = 0;
        if (t >= off) tv = sd[t - off];
        __syncthreads();
        if (t >= off) sd[t] += tv;
        __syncthreads();
    }
    if (t < NB_SCAN) bsum[t] = sd[t] - v;  // exclusive
}

__global__ void k_scan3(const unsigned int* __restrict__ cnt, const unsigned int* __restrict__ bsum,
                        unsigned int* __restrict__ rowstart, unsigned int* __restrict__ cursor) {
    __shared__ unsigned int sd[SCAN_B];
    int i = blockIdx.x * SCAN_B + threadIdx.x;
    unsigned int v = (i < N_NODES) ? cnt[i] : 0u;
    sd[threadIdx.x] = v;
    __syncthreads();
    for (int off = 1; off < SCAN_B; off <<= 1) {
        unsigned int tv = 0;
        if (threadIdx.x >= off) tv = sd[threadIdx.x - off];
        __syncthreads();
        if (threadIdx.x >= off) sd[threadIdx.x] += tv;
        __syncthreads();
    }
    if (i < N_NODES) {
        unsigned int rs = bsum[blockIdx.x] + sd[threadIdx.x] - v;  // exclusive
        rowstart[i] = rs;
        cursor[i] = rs;
    }
}

// fill CSR column (src) lists
__global__ void k_fill(const int* __restrict__ src, const int* __restrict__ dst,
                       unsigned int* __restrict__ cursor, int* __restrict__ col) {
    int e = blockIdx.x * blockDim.x + threadIdx.x;
    if (e < N_EDGES) {
        unsigned int pos = atomicAdd(&cursor[dst[e]], 1u);
        col[pos] = src[e];
    }
}

// ---------------- layer 1 (fused gather + MLP) ----------------
// t = dinv*(sum_{src} s[src] + s[n]); h1 = relu(t*W1+b1); q[n,:] = (h1@W2)*dinv
__global__ void k_layer1(const unsigned int* __restrict__ rowstart, const unsigned int* __restrict__ cnt,
                         const int* __restrict__ col,
                         const float* __restrict__ dinv, const float* __restrict__ s,
                         const float* __restrict__ W1, const float* __restrict__ b1,
                         const float* __restrict__ W2,
                         float* __restrict__ q) {
    __shared__ float sW2[64 * 32];
    __shared__ float sW1[64];
    __shared__ float sb1[64];
    for (int i = threadIdx.x; i < 64 * 32; i += blockDim.x) sW2[i] = W2[i];
    if (threadIdx.x < 64) { sW1[threadIdx.x] = W1[threadIdx.x]; sb1[threadIdx.x] = b1[threadIdx.x]; }
    __syncthreads();

    int n = blockIdx.x * blockDim.x + threadIdx.x;
    if (n >= N_NODES) return;

    unsigned int rs = rowstart[n];
    unsigned int c = cnt[n];
    float a = 0.0f;
    for (unsigned int i = 0; i < c; i++) a += s[col[rs + i]];

    float di = dinv[n];
    float t = di * (a + s[n]);

    float p[32];
#pragma unroll
    for (int k = 0; k < 32; k++) p[k] = 0.0f;
    for (int j = 0; j < 64; j++) {
        float h = fmaxf(t * sW1[j] + sb1[j], 0.0f);
#pragma unroll
        for (int k = 0; k < 32; k++) p[k] += h * sW2[j * 32 + k];
    }
#pragma unroll
    for (int k = 0; k < 32; k++) q[(size_t)n * 32 + k] = p[k] * di;
}

// ---------------- layer 2 gather (32 lanes per dst node) + relu ----------------
__global__ void k_gatherB(const unsigned int* __restrict__ rowstart, const unsigned int* __restrict__ cnt,
                          const int* __restrict__ col,
                          const float* __restrict__ q, const float* __restrict__ dinv,
                          const float* __restrict__ b2,
                          float* __restrict__ out2) {
    int n = blockIdx.x * (blockDim.x >> 5) + (threadIdx.x >> 5);
    int k = threadIdx.x & 31;
    if (n >= N_NODES) return;
    unsigned int rs = rowstart[n];
    unsigned int c = cnt[n];
    float acc = 0.0f;
    for (unsigned int i = 0; i < c; i++) {
        int si = col[rs + i];               // broadcast within the 32-lane group
        acc += q[(size_t)si * 32 + k];      // coalesced 128B row
    }
    float v = fmaxf(dinv[n] * (acc + q[(size_t)n * 32 + k]) + b2[k], 0.0f);
    out2[(size_t)n * 32 + k] = v;
}

// ---------------- pooling: register-run accumulation over sorted batch ----------------
__global__ void k_pool(const float* __restrict__ out2, const int* __restrict__ batch,
                       float* __restrict__ gsum, int chunk) {
    int gid = blockIdx.x * (blockDim.x >> 5) + (threadIdx.x >> 5);
    int k = threadIdx.x & 31;
    int n0 = gid * chunk;
    if (n0 >= N_NODES) return;
    int n1 = n0 + chunk; if (n1 > N_NODES) n1 = N_NODES;
    int cur = batch[n0];
    float acc = 0.0f;
    for (int n = n0; n < n1; n++) {
        int b = batch[n];
        if (b != cur) { atomicAdd(&gsum[cur * 32 + k], acc); acc = 0.0f; cur = b; }
        acc += out2[(size_t)n * 32 + k];
    }
    atomicAdd(&gsum[cur * 32 + k], acc);
}

// ---------------- readout ----------------
__global__ void k_readout(const float* __restrict__ gsum, const float* __restrict__ gcnt,
                          const float* __restrict__ Wfc, const float* __restrict__ bfc,
                          float* __restrict__ out) {
    int b = threadIdx.x;
    if (b < N_GRAPHS) {
        float inv = 1.0f / fmaxf(gcnt[b], 1.0f);
        float acc = bfc[0];
#pragma unroll
        for (int k = 0; k < 32; k++) acc += gsum[b * 32 + k] * inv * Wfc[k];
        out[b] = 1.0f / (1.0f + expf(-acc));
    }
}

// ---------------- launch ----------------

extern "C" void kernel_launch(void* const* d_in, const int* in_sizes, int n_in,
                              void* d_out, int out_size, void* d_ws, size_t ws_size,
                              hipStream_t stream) {
    const float* x    = (const float*)d_in[0];
    const int*   ei   = (const int*)d_in[1];
    const int*   batch= (const int*)d_in[2];
    const float* W1   = (const float*)d_in[3];
    const float* b1   = (const float*)d_in[4];
    const float* W2   = (const float*)d_in[5];
    const float* b2   = (const float*)d_in[6];
    const float* Wfc  = (const float*)d_in[7];
    const float* bfc  = (const float*)d_in[8];
    float* out = (float*)d_out;

    const int* srcIdx = ei;
    const int* dstIdx = ei + N_EDGES;

    char* w = (char*)d_ws;
    unsigned int* cnt      = (unsigned int*)w; w += (size_t)N_NODES * 4;
    unsigned int* rowstart = (unsigned int*)w; w += (size_t)N_NODES * 4;
    unsigned int* cursor   = (unsigned int*)w; w += (size_t)N_NODES * 4;
    unsigned int* bsum     = (unsigned int*)w; w += 512 * 4;
    float* dinv = (float*)w;                   w += (size_t)N_NODES * 4;
    float* sbuf = (float*)w;                   w += (size_t)N_NODES * 4;
    int*   col  = (int*)w;                     w += (size_t)N_EDGES * 4;
    float* q    = (float*)w;                   w += (size_t)N_NODES * 32 * 4;
    float* out2 = (float*)w;                   w += (size_t)N_NODES * 32 * 4;
    float* gsum = (float*)w;                   w += (size_t)N_GRAPHS * 32 * 4;
    float* gcnt = (float*)w;                   w += (size_t)N_GRAPHS * 4;

    hipMemsetAsync(cnt, 0, (size_t)N_NODES * 4, stream);
    hipMemsetAsync(gsum, 0, (size_t)N_GRAPHS * 32 * 4, stream);

    const int B = 256;
    k_hist  <<<(N_EDGES + B - 1) / B, B, 0, stream>>>(dstIdx, cnt);
    k_dinv_s<<<(N_NODES + B - 1) / B, B, 0, stream>>>(cnt, x, dinv, sbuf);
    k_gcnt  <<<1, 128, 0, stream>>>(batch, gcnt);
    k_scan1 <<<NB_SCAN, SCAN_B, 0, stream>>>(cnt, bsum);
    k_scan2 <<<1, 512, 0, stream>>>(bsum);
    k_scan3 <<<NB_SCAN, SCAN_B, 0, stream>>>(cnt, bsum, rowstart, cursor);
    k_fill  <<<(N_EDGES + B - 1) / B, B, 0, stream>>>(srcIdx, dstIdx, cursor, col);
    k_layer1<<<(N_NODES + B - 1) / B, B, 0, stream>>>(rowstart, cnt, col, dinv, sbuf, W1, b1, W2, q);

    int nodes_per_block = B / 32;  // 8
    k_gatherB<<<(N_NODES + nodes_per_block - 1) / nodes_per_block, B, 0, stream>>>(
        rowstart, cnt, col, q, dinv, b2, out2);

    int ngroups = 1000;             // 125 blocks * 8 groups
    int chunk = (N_NODES + ngroups - 1) / ngroups;  // 100
    k_pool<<<125, B, 0, stream>>>(out2, batch, gsum, chunk);

    k_readout<<<1, 64, 0, stream>>>(gsum, gcnt, Wfc, bfc, out);
}